// Round 11
// baseline (6495.161 us; speedup 1.0000x reference)
//
#include <hip/hip_runtime.h>
#include <hip/hip_bf16.h>
#include <cstddef>
#include <cstdint>

#define DEV __device__ __forceinline__

DEV float lrelu_f(float z){ return z >= 0.f ? z : 0.1f*z; }

// ---------------- K1: encoder conv1 (y -> e1), 3x3 s2 p1 + bias + BN + lrelu ----
__global__ __launch_bounds__(256) void k_enc1(
    const float* __restrict__ y, const float* __restrict__ w,
    const float* __restrict__ bias, const float* __restrict__ g,
    const float* __restrict__ bb, const float* __restrict__ m,
    const float* __restrict__ v, float* __restrict__ e1)
{
    int idx = blockIdx.x*256 + threadIdx.x;     // [4,128,32,32]
    int ow = idx & 31, oh = (idx>>5)&31, co = (idx>>10)&127, b = idx>>17;
    float acc = 0.f;
    const float* wp = w + co*576;
    const float* yb = y + (size_t)b*64*4096;
    for (int ci=0; ci<64; ++ci){
        const float* yp = yb + ci*4096;
        const float* wr = wp + ci*9;
        #pragma unroll
        for (int kh=0; kh<3; ++kh){
            int ih = oh*2 + kh - 1;
            if (ih < 0 || ih > 63) continue;
            #pragma unroll
            for (int kw=0; kw<3; ++kw){
                int iw = ow*2 + kw - 1;
                if (iw < 0 || iw > 63) continue;
                acc += yp[ih*64+iw] * wr[kh*3+kw];
            }
        }
    }
    float s = g[co] / sqrtf(v[co] + 1e-5f);
    float val = (acc + bias[co] - m[co])*s + bb[co];
    e1[idx] = lrelu_f(val);
}

// ---------------- K2: encoder conv2 (e1 -> per-(b,co) mean), 3x3 s1 p0 --------
__global__ __launch_bounds__(256) void k_enc2(
    const float* __restrict__ e1, const float* __restrict__ w,
    const float* __restrict__ bias, const float* __restrict__ g,
    const float* __restrict__ bb, const float* __restrict__ m,
    const float* __restrict__ v, float* __restrict__ fvec)
{
    __shared__ float red[256];
    int co = blockIdx.x, b = blockIdx.y, tid = threadIdx.x;
    float s  = g[co] / sqrtf(v[co] + 1e-5f);
    float bs = (bias[co]-m[co])*s + bb[co];
    const float* wp = w + co*1152;
    float lsum = 0.f;
    const float* eb = e1 + (size_t)b*128*1024;
    for (int p=tid; p<900; p+=256){
        int oh = p/30, ow = p - oh*30;
        float acc = 0.f;
        const float* ep = eb + oh*32 + ow;
        for (int ci=0; ci<128; ++ci){
            const float* row = ep + ci*1024;
            const float* wr  = wp + ci*9;
            acc += row[0]*wr[0]  + row[1]*wr[1]  + row[2]*wr[2]
                 + row[32]*wr[3] + row[33]*wr[4] + row[34]*wr[5]
                 + row[64]*wr[6] + row[65]*wr[7] + row[66]*wr[8];
        }
        lsum += lrelu_f(acc*s + bs);
    }
    red[tid] = lsum; __syncthreads();
    for (int st=128; st>0; st>>=1){
        if (tid < st) red[tid] += red[tid+st];
        __syncthreads();
    }
    if (tid==0) fvec[b*256+co] = red[0] * (1.f/900.f);
}

// ---------------- K3: MLP + kernel-prediction head ---------------------------
__global__ __launch_bounds__(256) void k_mlp(
    const float* __restrict__ fvec,
    const float* __restrict__ mw1, const float* __restrict__ mb1,
    const float* __restrict__ mw2, const float* __restrict__ mb2,
    const float* __restrict__ kw1, const float* __restrict__ kw2,
    float* __restrict__ kern)
{
    __shared__ float fs[256], h1[256], emb[256], k1[128];
    int b = blockIdx.x, t = threadIdx.x;
    fs[t] = fvec[b*256+t];
    __syncthreads();
    {
        float acc = mb1[t];
        const float* wr = mw1 + t*256;
        for (int i=0;i<256;++i) acc += fs[i]*wr[i];
        h1[t] = lrelu_f(acc);
    }
    __syncthreads();
    {
        float acc = mb2[t];
        const float* wr = mw2 + t*256;
        for (int i=0;i<256;++i) acc += h1[i]*wr[i];
        emb[t] = acc;
    }
    __syncthreads();
    if (t < 128){
        float acc = 0.f;
        const float* wr = kw1 + t*256;
        for (int i=0;i<256;++i) acc += emb[i]*wr[i];
        k1[t] = lrelu_f(acc);
    }
    __syncthreads();
    for (int o=t; o<576; o+=256){
        float acc = 0.f;
        const float* wr = kw2 + o*128;
        for (int i=0;i<128;++i) acc += k1[i]*wr[i];
        kern[b*576+o] = acc;
    }
}

// ---------------- K4a: dynamic depthwise conv + lrelu (per-element) ----------
__global__ __launch_bounds__(256) void k_dw(
    const float* __restrict__ x, const float* __restrict__ kern,
    __hip_bfloat16* __restrict__ dwb)
{
    int idx = blockIdx.x*256 + threadIdx.x;      // [4,64,256,256]
    int ow = idx & 255, oh = (idx>>8)&255, c = (idx>>16)&63, b = idx>>22;
    const float* kr = kern + b*576 + c*9;
    const float* xp = x + ((size_t)(b*64+c) << 16);
    float acc = 0.f;
    #pragma unroll
    for (int kh=0; kh<3; ++kh){
        int ih = oh + kh - 1;
        if (ih < 0 || ih > 255) continue;
        #pragma unroll
        for (int kw=0; kw<3; ++kw){
            int iw = ow + kw - 1;
            if (iw < 0 || iw > 255) continue;
            acc += xp[ih*256+iw] * kr[kh*3+kw];
        }
    }
    dwb[idx] = __float2bfloat16(lrelu_f(acc));
}

// ---------------- K4b: per-pixel {1x1(dw) + CA + combine + lrelu}, in-place ---
__global__ __launch_bounds__(256) void k_pre(
    const float* __restrict__ x, __hip_bfloat16* __restrict__ buf,
    const float* __restrict__ cw, const float* __restrict__ cb,
    const float* __restrict__ caw1, const float* __restrict__ caw2)
{
    int idx = blockIdx.x*256 + threadIdx.x;      // [4, 65536] pixels
    int px = idx & 65535, b = idx >> 16;
    size_t base = ((size_t)b << 22) + px;
    float dwr[64];
    float a1[32];
    #pragma unroll
    for (int j=0;j<32;++j) a1[j] = 0.f;
    for (int ci=0; ci<64; ++ci){
        size_t o = base + ((size_t)ci<<16);
        float xv = x[o];
        dwr[ci] = __bfloat162float(buf[o]);
        #pragma unroll
        for (int j=0;j<32;++j) a1[j] += xv * caw1[j*64+ci];
    }
    #pragma unroll
    for (int j=0;j<32;++j) a1[j] = lrelu_f(a1[j]);
    for (int o=0; o<64; ++o){
        float att = 0.f;
        #pragma unroll
        for (int j=0;j<32;++j) att += a1[j] * caw2[o*32+j];
        att = fmaxf(att, 0.f);
        float dyn = 0.f;
        for (int ci=0;ci<64;++ci) dyn += dwr[ci] * cw[o*64+ci];
        size_t oi = base + ((size_t)o<<16);
        float xv = x[oi];
        buf[oi] = __float2bfloat16(lrelu_f(dyn + cb[o] + xv*att));
    }
}

// ---------------- K5: simple 64->64 3x3 conv, one thread per output element ---
// TIN: input element type (bf16 or float). Residual (f32) optional. ACT: relu.
template<typename TIN, int STRIDE, int RES, int ACT>
__global__ __launch_bounds__(256) void k_conv3s(
    const TIN* __restrict__ in, const float* __restrict__ w,
    const float* __restrict__ bias, const float* __restrict__ res,
    float* __restrict__ out,
    int H, int W, int Ho, int Wo, int total)
{
    int idx = blockIdx.x*256 + threadIdx.x;
    if (idx >= total) return;
    int ow = idx % Wo;
    int t  = idx / Wo;
    int oh = t % Ho;  t /= Ho;
    int co = t & 63;
    int b  = t >> 6;
    const float* wp = w + co*576;
    float acc = 0.f;
    for (int ci=0; ci<64; ++ci){
        const TIN* ip = in + ((size_t)(b*64+ci))*H*W;
        const float* wr = wp + ci*9;
        #pragma unroll
        for (int kh=0; kh<3; ++kh){
            int ih = oh*STRIDE + kh - 1;
            if (ih < 0 || ih >= H) continue;
            #pragma unroll
            for (int kw=0; kw<3; ++kw){
                int iw = ow*STRIDE + kw - 1;
                if (iw < 0 || iw >= W) continue;
                float iv;
                if constexpr (sizeof(TIN) == 2) iv = __bfloat162float(ip[(size_t)ih*W+iw]);
                else                            iv = ((const float*)ip)[(size_t)ih*W+iw];
                acc += iv * wr[kh*3+kw];
            }
        }
    }
    acc += bias[co];
    if (ACT==1) acc = fmaxf(acc, 0.f);
    if (RES==1) acc += res[idx];
    out[idx] = acc;
}

// ---------------- host ---------------------------------------------------------
extern "C" void kernel_launch(void* const* d_in, const int* in_sizes, int n_in,
                              void* d_out, int out_size, void* d_ws, size_t ws_size,
                              hipStream_t stream) {
    const float* x    = (const float*)d_in[0];
    const float* y    = (const float*)d_in[1];
    const float* ew1  = (const float*)d_in[2];
    const float* eb1  = (const float*)d_in[3];
    const float* bn1g = (const float*)d_in[4];
    const float* bn1b = (const float*)d_in[5];
    const float* bn1m = (const float*)d_in[6];
    const float* bn1v = (const float*)d_in[7];
    const float* ew2  = (const float*)d_in[8];
    const float* eb2  = (const float*)d_in[9];
    const float* bn2g = (const float*)d_in[10];
    const float* bn2b = (const float*)d_in[11];
    const float* bn2m = (const float*)d_in[12];
    const float* bn2v = (const float*)d_in[13];
    const float* mw1  = (const float*)d_in[14];
    const float* mb1  = (const float*)d_in[15];
    const float* mw2  = (const float*)d_in[16];
    const float* mb2  = (const float*)d_in[17];
    const float* kw1  = (const float*)d_in[18];
    const float* kw2  = (const float*)d_in[19];
    const float* cw   = (const float*)d_in[20];
    const float* cb   = (const float*)d_in[21];
    const float* caw1 = (const float*)d_in[22];
    const float* caw2 = (const float*)d_in[23];
    const float* c1w  = (const float*)d_in[24];
    const float* c1b  = (const float*)d_in[25];
    const float* c2w  = (const float*)d_in[26];
    const float* c2b  = (const float*)d_in[27];
    const float* r1w  = (const float*)d_in[28];
    const float* r1b  = (const float*)d_in[29];
    const float* r2w  = (const float*)d_in[30];
    const float* r2b  = (const float*)d_in[31];

    // ws layout (~33.6 MB):
    //   buf bf16 [0, 33554432)  (dw -> pre in place; dead after out0-conv)
    //     e1 f32 overlays [0, 2097152)  (dead before k_dw)
    //     after buf dies: t2 f32 [0,16777216), u2 f32 [16777216,33554432)
    //     after out2:     t3 f32 [0,4194304),  u3 f32 [4194304,8388608)
    //   fv  f32 @ 33554432
    //   kern f32 @ 33558528
    char* wsc = (char*)d_ws;
    __hip_bfloat16* buf = (__hip_bfloat16*)wsc;
    float*          e1  = (float*)wsc;
    float*          t2  = (float*)wsc;
    float*          u2  = (float*)(wsc + 16777216);
    float*          t3  = (float*)wsc;
    float*          u3  = (float*)(wsc + 4194304);
    float*          fv  = (float*)(wsc + 33554432);
    float*          kern= (float*)(wsc + 33558528);

    float* ob   = (float*)d_out;            // out  (4,64,256,256) f32
    float* ob1  = ob + 16777216;            // out2 (4,64,128,128) f32
    float* ob2  = ob + 20971520;            // out3 (4,64,64,64)   f32

    k_enc1<<<dim3(2048),256,0,stream>>>(y, ew1, eb1, bn1g, bn1b, bn1m, bn1v, e1);
    k_enc2<<<dim3(256,4),256,0,stream>>>(e1, ew2, eb2, bn2g, bn2b, bn2m, bn2v, fv);
    k_mlp<<<dim3(4),256,0,stream>>>(fv, mw1, mb1, mw2, mb2, kw1, kw2, kern);
    k_dw <<<dim3(65536),256,0,stream>>>(x, kern, buf);
    k_pre<<<dim3(1024),256,0,stream>>>(x, buf, cw, cb, caw1, caw2);

    // out = conv3x3(pre) + bias + x  -> d_out seg0 (f32)
    k_conv3s<__hip_bfloat16,1,1,0><<<dim3(65536),256,0,stream>>>(buf, c1w, c1b, x, ob, 256,256,256,256, 16777216);
    // t2 = conv3x3 s2 (out)
    k_conv3s<float,2,0,0><<<dim3(16384),256,0,stream>>>(ob, c2w, c2b, nullptr, t2, 256,256,128,128, 4194304);
    // u2 = relu(conv3x3(t2))
    k_conv3s<float,1,0,1><<<dim3(16384),256,0,stream>>>(t2, r1w, r1b, nullptr, u2, 128,128,128,128, 4194304);
    // out2 = t2 + conv3x3(u2)  -> d_out seg1
    k_conv3s<float,1,1,0><<<dim3(16384),256,0,stream>>>(u2, r2w, r2b, t2, ob1, 128,128,128,128, 4194304);
    // t3 = conv3x3 s2 (out2)
    k_conv3s<float,2,0,0><<<dim3(4096),256,0,stream>>>(ob1, c2w, c2b, nullptr, t3, 128,128,64,64, 1048576);
    // u3 = relu(conv3x3(t3))
    k_conv3s<float,1,0,1><<<dim3(4096),256,0,stream>>>(t3, r1w, r1b, nullptr, u3, 64,64,64,64, 1048576);
    // out3 = t3 + conv3x3(u3)  -> d_out seg2
    k_conv3s<float,1,1,0><<<dim3(4096),256,0,stream>>>(u3, r2w, r2b, t3, ob2, 64,64,64,64, 1048576);
}

// Round 12
// 1186.757 us; speedup vs baseline: 5.4730x; 5.4730x over previous
//
#include <hip/hip_runtime.h>
#include <hip/hip_bf16.h>
#include <cstddef>
#include <cstdint>

#define DEV __device__ __forceinline__

DEV float lrelu_f(float z){ return z >= 0.f ? z : 0.1f*z; }

typedef __bf16 bf16x8 __attribute__((ext_vector_type(8)));
typedef float  f32x4  __attribute__((ext_vector_type(4)));

DEV unsigned short bf_bits(float v){
    __hip_bfloat16 h = __float2bfloat16(v);
    unsigned short s; __builtin_memcpy(&s, &h, 2); return s;
}
DEV unsigned short bf_bits(__hip_bfloat16 v){
    unsigned short s; __builtin_memcpy(&s, &v, 2); return s;
}

// ---------------- K1: encoder conv1 (y -> e1), 3x3 s2 p1 + bias + BN + lrelu ----
__global__ __launch_bounds__(256) void k_enc1(
    const float* __restrict__ y, const float* __restrict__ w,
    const float* __restrict__ bias, const float* __restrict__ g,
    const float* __restrict__ bb, const float* __restrict__ m,
    const float* __restrict__ v, float* __restrict__ e1)
{
    int idx = blockIdx.x*256 + threadIdx.x;     // [4,128,32,32]
    int ow = idx & 31, oh = (idx>>5)&31, co = (idx>>10)&127, b = idx>>17;
    float acc = 0.f;
    const float* wp = w + co*576;
    const float* yb = y + (size_t)b*64*4096;
    for (int ci=0; ci<64; ++ci){
        const float* yp = yb + ci*4096;
        const float* wr = wp + ci*9;
        #pragma unroll
        for (int kh=0; kh<3; ++kh){
            int ih = oh*2 + kh - 1;
            if (ih < 0 || ih > 63) continue;
            #pragma unroll
            for (int kw=0; kw<3; ++kw){
                int iw = ow*2 + kw - 1;
                if (iw < 0 || iw > 63) continue;
                acc += yp[ih*64+iw] * wr[kh*3+kw];
            }
        }
    }
    float s = g[co] / sqrtf(v[co] + 1e-5f);
    float val = (acc + bias[co] - m[co])*s + bb[co];
    e1[idx] = lrelu_f(val);
}

// ---------------- K2: encoder conv2 (e1 -> per-(b,co) mean), 3x3 s1 p0 --------
__global__ __launch_bounds__(256) void k_enc2(
    const float* __restrict__ e1, const float* __restrict__ w,
    const float* __restrict__ bias, const float* __restrict__ g,
    const float* __restrict__ bb, const float* __restrict__ m,
    const float* __restrict__ v, float* __restrict__ fvec)
{
    __shared__ float red[256];
    int co = blockIdx.x, b = blockIdx.y, tid = threadIdx.x;
    float s  = g[co] / sqrtf(v[co] + 1e-5f);
    float bs = (bias[co]-m[co])*s + bb[co];
    const float* wp = w + co*1152;
    float lsum = 0.f;
    const float* eb = e1 + (size_t)b*128*1024;
    for (int p=tid; p<900; p+=256){
        int oh = p/30, ow = p - oh*30;
        float acc = 0.f;
        const float* ep = eb + oh*32 + ow;
        for (int ci=0; ci<128; ++ci){
            const float* row = ep + ci*1024;
            const float* wr  = wp + ci*9;
            acc += row[0]*wr[0]  + row[1]*wr[1]  + row[2]*wr[2]
                 + row[32]*wr[3] + row[33]*wr[4] + row[34]*wr[5]
                 + row[64]*wr[6] + row[65]*wr[7] + row[66]*wr[8];
        }
        lsum += lrelu_f(acc*s + bs);
    }
    red[tid] = lsum; __syncthreads();
    for (int st=128; st>0; st>>=1){
        if (tid < st) red[tid] += red[tid+st];
        __syncthreads();
    }
    if (tid==0) fvec[b*256+co] = red[0] * (1.f/900.f);
}

// ---------------- K3: MLP + kernel-prediction head ---------------------------
__global__ __launch_bounds__(256) void k_mlp(
    const float* __restrict__ fvec,
    const float* __restrict__ mw1, const float* __restrict__ mb1,
    const float* __restrict__ mw2, const float* __restrict__ mb2,
    const float* __restrict__ kw1, const float* __restrict__ kw2,
    float* __restrict__ kern)
{
    __shared__ float fs[256], h1[256], emb[256], k1[128];
    int b = blockIdx.x, t = threadIdx.x;
    fs[t] = fvec[b*256+t];
    __syncthreads();
    {
        float acc = mb1[t];
        const float* wr = mw1 + t*256;
        for (int i=0;i<256;++i) acc += fs[i]*wr[i];
        h1[t] = lrelu_f(acc);
    }
    __syncthreads();
    {
        float acc = mb2[t];
        const float* wr = mw2 + t*256;
        for (int i=0;i<256;++i) acc += h1[i]*wr[i];
        emb[t] = acc;
    }
    __syncthreads();
    if (t < 128){
        float acc = 0.f;
        const float* wr = kw1 + t*256;
        for (int i=0;i<256;++i) acc += emb[i]*wr[i];
        k1[t] = lrelu_f(acc);
    }
    __syncthreads();
    for (int o=t; o<576; o+=256){
        float acc = 0.f;
        const float* wr = kw2 + o*128;
        for (int i=0;i<128;++i) acc += k1[i]*wr[i];
        kern[b*576+o] = acc;
    }
}

// ---------------- K4a: dynamic depthwise conv + lrelu (per-element) ----------
__global__ __launch_bounds__(256) void k_dw(
    const float* __restrict__ x, const float* __restrict__ kern,
    __hip_bfloat16* __restrict__ dwb)
{
    int idx = blockIdx.x*256 + threadIdx.x;      // [4,64,256,256]
    int ow = idx & 255, oh = (idx>>8)&255, c = (idx>>16)&63, b = idx>>22;
    const float* kr = kern + b*576 + c*9;
    const float* xp = x + ((size_t)(b*64+c) << 16);
    float acc = 0.f;
    #pragma unroll
    for (int kh=0; kh<3; ++kh){
        int ih = oh + kh - 1;
        if (ih < 0 || ih > 255) continue;
        #pragma unroll
        for (int kw=0; kw<3; ++kw){
            int iw = ow + kw - 1;
            if (iw < 0 || iw > 255) continue;
            acc += xp[ih*256+iw] * kr[kh*3+kw];
        }
    }
    dwb[idx] = __float2bfloat16(lrelu_f(acc));
}

// ---------------- K4b: per-pixel {1x1(dw) + CA + combine + lrelu}, in-place ---
__global__ __launch_bounds__(256) void k_pre(
    const float* __restrict__ x, __hip_bfloat16* __restrict__ buf,
    const float* __restrict__ cw, const float* __restrict__ cb,
    const float* __restrict__ caw1, const float* __restrict__ caw2)
{
    int idx = blockIdx.x*256 + threadIdx.x;      // [4, 65536] pixels
    int px = idx & 65535, b = idx >> 16;
    size_t base = ((size_t)b << 22) + px;
    float dwr[64];
    float a1[32];
    #pragma unroll
    for (int j=0;j<32;++j) a1[j] = 0.f;
    for (int ci=0; ci<64; ++ci){
        size_t o = base + ((size_t)ci<<16);
        float xv = x[o];
        dwr[ci] = __bfloat162float(buf[o]);
        #pragma unroll
        for (int j=0;j<32;++j) a1[j] += xv * caw1[j*64+ci];
    }
    #pragma unroll
    for (int j=0;j<32;++j) a1[j] = lrelu_f(a1[j]);
    for (int o=0; o<64; ++o){
        float att = 0.f;
        #pragma unroll
        for (int j=0;j<32;++j) att += a1[j] * caw2[o*32+j];
        att = fmaxf(att, 0.f);
        float dyn = 0.f;
        for (int ci=0;ci<64;++ci) dyn += dwr[ci] * cw[o*64+ci];
        size_t oi = base + ((size_t)o<<16);
        float xv = x[oi];
        buf[oi] = __float2bfloat16(lrelu_f(dyn + cb[o] + xv*att));
    }
}

// ---------------- K5: MFMA implicit-GEMM 64->64 3x3 conv ----------------------
// Block: 4x16 output px x 64 co, 4 waves. Wave w: co in [w*16, w*16+16).
// MFMA 16x16x32 bf16: A = weights (M=16co x K=32ci), B = activations
// (K=32ci x N=16px). C: col(lane&15)=px, row((lane>>4)*4+r)=co  -> coalesced
// NCHW stores. A-tile in LDS [row][col][ci] with 16B-slot XOR swizzle.
// RESMODE: 0 none, 1 f32 residual, 2 bf16 residual. OUTBF: 1 bf16 out, 0 f32.
template<typename TIN, int STRIDE, int RESMODE, int ACT, int OUTBF>
__global__ __launch_bounds__(256) void k_conv_mfma(
    const TIN* __restrict__ in, const float* __restrict__ w,
    const float* __restrict__ bias, const void* __restrict__ res,
    void* __restrict__ outp, int H, int W, int Ho, int Wo)
{
    constexpr int ROWS = (STRIDE==1) ? 6 : 9;
    constexpr int COLS = (STRIDE==1) ? 18 : 33;
    __shared__ __align__(16) char lA[ROWS*COLS*8*16];   // [row][col][slot^..][8 bf16]
    __shared__ __align__(16) char lW[64*4*16];          // [co][slot^..][8 bf16]
    const int tid  = threadIdx.x;
    const int wid  = tid >> 6, lane = tid & 63;
    const int b    = blockIdx.y;
    const int tilesW = Wo >> 4;
    const int toh  = (blockIdx.x / tilesW) * 4;
    const int tow  = (blockIdx.x % tilesW) * 16;
    const int row0 = toh*STRIDE - 1;
    const int col0 = tow*STRIDE - 1;

    // ---- stage A: full 64-ci spatial window, transposed to [row][col][ci] ----
    for (int i = tid; i < ROWS*COLS*64; i += 256){
        int c  = i % COLS;
        int t  = i / COLS;
        int r  = t % ROWS;
        int ci = t / ROWS;
        int ih = row0 + r, iw = col0 + c;
        unsigned short bits = 0;
        if (ih >= 0 && ih < H && iw >= 0 && iw < W)
            bits = bf_bits(in[((size_t)(b*64+ci))*H*W + (size_t)ih*W + iw]);
        int slot = ci >> 3, e = ci & 7;
        *(unsigned short*)(lA + ((r*COLS + c)*8 + (slot ^ (c & 7)))*16 + e*2) = bits;
    }
    f32x4 acc[4] = {{0.f,0.f,0.f,0.f},{0.f,0.f,0.f,0.f},{0.f,0.f,0.f,0.f},{0.f,0.f,0.f,0.f}};
    __syncthreads();

    const int px  = lane & 15;
    const int g   = lane >> 4;
    const int coA = wid*16 + (lane & 15);                 // A-frag row = lane&15
    const int wAoff = (coA*4 + (g ^ ((coA>>1)&3)))*16;

    for (int ch = 0; ch < 2; ++ch){
        #pragma unroll
        for (int pos = 0; pos < 9; ++pos){
            // ---- stage W[ch,pos]: 64co x 32ci (f32 OIHW -> bf16 [co][ci]) ----
            for (int i = tid; i < 2048; i += 256){
                int co = i >> 5, cil = i & 31;
                float wv = w[((size_t)co*64 + ch*32 + cil)*9 + pos];
                int slot = cil >> 3, e = cil & 7;
                *(unsigned short*)(lW + (co*4 + (slot ^ ((co>>1)&3)))*16 + e*2) = bf_bits(wv);
            }
            __syncthreads();
            const int kh = pos/3, kw = pos - 3*(pos/3);
            bf16x8 aw = *(const bf16x8*)(lW + wAoff);
            const int cc = px*STRIDE + kw;
            const int boff = ((ch*4 + g) ^ (cc & 7))*16;
            #pragma unroll
            for (int n = 0; n < 4; ++n){
                int rr = n*STRIDE + kh;
                bf16x8 bx = *(const bf16x8*)(lA + (rr*COLS + cc)*128 + boff);
                acc[n] = __builtin_amdgcn_mfma_f32_16x16x32_bf16(aw, bx, acc[n], 0, 0, 0);
            }
            __syncthreads();
        }
    }

    // ---- epilogue: bias (+res) (+act) -> f32 or bf16 NCHW -------------------
    const int coBase = wid*16 + g*4;
    #pragma unroll
    for (int n = 0; n < 4; ++n){
        int oh = toh + n, ow = tow + px;
        #pragma unroll
        for (int r = 0; r < 4; ++r){
            int co = coBase + r;
            size_t oi = ((size_t)(b*64+co)*Ho + oh)*Wo + ow;
            float v = acc[n][r] + bias[co];
            if (ACT) v = fmaxf(v, 0.f);
            if (RESMODE == 1) v += ((const float*)res)[oi];
            if (RESMODE == 2) v += __bfloat162float(((const __hip_bfloat16*)res)[oi]);
            if (OUTBF) ((__hip_bfloat16*)outp)[oi] = __float2bfloat16(v);
            else       ((float*)outp)[oi] = v;
        }
    }
}

// ---------------- host ---------------------------------------------------------
extern "C" void kernel_launch(void* const* d_in, const int* in_sizes, int n_in,
                              void* d_out, int out_size, void* d_ws, size_t ws_size,
                              hipStream_t stream) {
    const float* x    = (const float*)d_in[0];
    const float* y    = (const float*)d_in[1];
    const float* ew1  = (const float*)d_in[2];
    const float* eb1  = (const float*)d_in[3];
    const float* bn1g = (const float*)d_in[4];
    const float* bn1b = (const float*)d_in[5];
    const float* bn1m = (const float*)d_in[6];
    const float* bn1v = (const float*)d_in[7];
    const float* ew2  = (const float*)d_in[8];
    const float* eb2  = (const float*)d_in[9];
    const float* bn2g = (const float*)d_in[10];
    const float* bn2b = (const float*)d_in[11];
    const float* bn2m = (const float*)d_in[12];
    const float* bn2v = (const float*)d_in[13];
    const float* mw1  = (const float*)d_in[14];
    const float* mb1  = (const float*)d_in[15];
    const float* mw2  = (const float*)d_in[16];
    const float* mb2  = (const float*)d_in[17];
    const float* kw1  = (const float*)d_in[18];
    const float* kw2  = (const float*)d_in[19];
    const float* cw   = (const float*)d_in[20];
    const float* cb   = (const float*)d_in[21];
    const float* caw1 = (const float*)d_in[22];
    const float* caw2 = (const float*)d_in[23];
    const float* c1w  = (const float*)d_in[24];
    const float* c1b  = (const float*)d_in[25];
    const float* c2w  = (const float*)d_in[26];
    const float* c2b  = (const float*)d_in[27];
    const float* r1w  = (const float*)d_in[28];
    const float* r1b  = (const float*)d_in[29];
    const float* r2w  = (const float*)d_in[30];
    const float* r2b  = (const float*)d_in[31];

    // ws layout (~33.6 MB, within proven budget):
    //   buf bf16 [0, 33554432)  (dw -> pre in place; dead after c1-conv)
    //     e1 f32 overlays [0, 2097152)   (dead before k_dw)
    //     after buf dies: t2 bf16 [0, 8388608), u2 bf16 [8388608, 16777216),
    //                     t3 bf16 [16777216, 18874368), u3 bf16 [18874368, 20971520)
    //   fv f32 @ 33554432, kern f32 @ 33558528
    char* wsc = (char*)d_ws;
    __hip_bfloat16* buf = (__hip_bfloat16*)wsc;
    float*          e1  = (float*)wsc;
    __hip_bfloat16* t2  = (__hip_bfloat16*)wsc;
    __hip_bfloat16* u2  = (__hip_bfloat16*)(wsc + 8388608);
    __hip_bfloat16* t3  = (__hip_bfloat16*)(wsc + 16777216);
    __hip_bfloat16* u3  = (__hip_bfloat16*)(wsc + 18874368);
    float*          fv  = (float*)(wsc + 33554432);
    float*          kern= (float*)(wsc + 33558528);

    float* ob   = (float*)d_out;            // out  (4,64,256,256) f32
    float* ob1  = ob + 16777216;            // out2 (4,64,128,128) f32
    float* ob2  = ob + 20971520;            // out3 (4,64,64,64)   f32

    k_enc1<<<dim3(2048),256,0,stream>>>(y, ew1, eb1, bn1g, bn1b, bn1m, bn1v, e1);
    k_enc2<<<dim3(256,4),256,0,stream>>>(e1, ew2, eb2, bn2g, bn2b, bn2m, bn2v, fv);
    k_mlp<<<dim3(4),256,0,stream>>>(fv, mw1, mb1, mw2, mb2, kw1, kw2, kern);
    k_dw <<<dim3(65536),256,0,stream>>>(x, kern, buf);
    k_pre<<<dim3(1024),256,0,stream>>>(x, buf, cw, cb, caw1, caw2);

    // out0 = conv3x3(pre) + bias + x  -> f32 d_out
    k_conv_mfma<__hip_bfloat16,1,1,0,0><<<dim3(64*16,4),256,0,stream>>>(buf, c1w, c1b, x, ob, 256,256,256,256);
    // t2 = conv3x3 s2 (out0, f32)     -> bf16 ws
    k_conv_mfma<float,2,0,0,1><<<dim3(32*8,4),256,0,stream>>>(ob, c2w, c2b, nullptr, t2, 256,256,128,128);
    // u2 = relu(conv3x3(t2))          -> bf16 ws
    k_conv_mfma<__hip_bfloat16,1,0,1,1><<<dim3(32*8,4),256,0,stream>>>(t2, r1w, r1b, nullptr, u2, 128,128,128,128);
    // out2 = t2 + conv3x3(u2)         -> f32 d_out
    k_conv_mfma<__hip_bfloat16,1,2,0,0><<<dim3(32*8,4),256,0,stream>>>(u2, r2w, r2b, t2, ob1, 128,128,128,128);
    // t3 = conv3x3 s2 (out2, f32)     -> bf16 ws
    k_conv_mfma<float,2,0,0,1><<<dim3(16*4,4),256,0,stream>>>(ob1, c2w, c2b, nullptr, t3, 128,128,64,64);
    // u3 = relu(conv3x3(t3))          -> bf16 ws
    k_conv_mfma<__hip_bfloat16,1,0,1,1><<<dim3(16*4,4),256,0,stream>>>(t3, r1w, r1b, nullptr, u3, 64,64,64,64);
    // out3 = t3 + conv3x3(u3)         -> f32 d_out
    k_conv_mfma<__hip_bfloat16,1,2,0,0><<<dim3(16*4,4),256,0,stream>>>(u3, r2w, r2b, t3, ob2, 64,64,64,64);
}

// Round 13
// 1017.764 us; speedup vs baseline: 6.3818x; 1.1660x over previous
//
#include <hip/hip_runtime.h>
#include <hip/hip_bf16.h>
#include <cstddef>
#include <cstdint>

#define DEV __device__ __forceinline__

DEV float lrelu_f(float z){ return z >= 0.f ? z : 0.1f*z; }

typedef __bf16 bf16x8 __attribute__((ext_vector_type(8)));
typedef float  f32x4  __attribute__((ext_vector_type(4)));

DEV unsigned short bf_bits(float v){
    __hip_bfloat16 h = __float2bfloat16(v);
    unsigned short s; __builtin_memcpy(&s, &h, 2); return s;
}
DEV unsigned short bf_bits(__hip_bfloat16 v){
    unsigned short s; __builtin_memcpy(&s, &v, 2); return s;
}
DEV float bf_val(const char* p){
    unsigned short s = *(const unsigned short*)p;
    __hip_bfloat16 h; __builtin_memcpy(&h, &s, 2);
    return __bfloat162float(h);
}

// ---------------- K1: encoder conv1 (y -> e1), 3x3 s2 p1 + bias + BN + lrelu ----
__global__ __launch_bounds__(256) void k_enc1(
    const float* __restrict__ y, const float* __restrict__ w,
    const float* __restrict__ bias, const float* __restrict__ g,
    const float* __restrict__ bb, const float* __restrict__ m,
    const float* __restrict__ v, float* __restrict__ e1)
{
    int idx = blockIdx.x*256 + threadIdx.x;     // [4,128,32,32]
    int ow = idx & 31, oh = (idx>>5)&31, co = (idx>>10)&127, b = idx>>17;
    float acc = 0.f;
    const float* wp = w + co*576;
    const float* yb = y + (size_t)b*64*4096;
    for (int ci=0; ci<64; ++ci){
        const float* yp = yb + ci*4096;
        const float* wr = wp + ci*9;
        #pragma unroll
        for (int kh=0; kh<3; ++kh){
            int ih = oh*2 + kh - 1;
            if (ih < 0 || ih > 63) continue;
            #pragma unroll
            for (int kw=0; kw<3; ++kw){
                int iw = ow*2 + kw - 1;
                if (iw < 0 || iw > 63) continue;
                acc += yp[ih*64+iw] * wr[kh*3+kw];
            }
        }
    }
    float s = g[co] / sqrtf(v[co] + 1e-5f);
    float val = (acc + bias[co] - m[co])*s + bb[co];
    e1[idx] = lrelu_f(val);
}

// ---------------- K2: encoder conv2 (e1 -> per-(b,co) mean), 3x3 s1 p0 --------
__global__ __launch_bounds__(256) void k_enc2(
    const float* __restrict__ e1, const float* __restrict__ w,
    const float* __restrict__ bias, const float* __restrict__ g,
    const float* __restrict__ bb, const float* __restrict__ m,
    const float* __restrict__ v, float* __restrict__ fvec)
{
    __shared__ float red[256];
    int co = blockIdx.x, b = blockIdx.y, tid = threadIdx.x;
    float s  = g[co] / sqrtf(v[co] + 1e-5f);
    float bs = (bias[co]-m[co])*s + bb[co];
    const float* wp = w + co*1152;
    float lsum = 0.f;
    const float* eb = e1 + (size_t)b*128*1024;
    for (int p=tid; p<900; p+=256){
        int oh = p/30, ow = p - oh*30;
        float acc = 0.f;
        const float* ep = eb + oh*32 + ow;
        for (int ci=0; ci<128; ++ci){
            const float* row = ep + ci*1024;
            const float* wr  = wp + ci*9;
            acc += row[0]*wr[0]  + row[1]*wr[1]  + row[2]*wr[2]
                 + row[32]*wr[3] + row[33]*wr[4] + row[34]*wr[5]
                 + row[64]*wr[6] + row[65]*wr[7] + row[66]*wr[8];
        }
        lsum += lrelu_f(acc*s + bs);
    }
    red[tid] = lsum; __syncthreads();
    for (int st=128; st>0; st>>=1){
        if (tid < st) red[tid] += red[tid+st];
        __syncthreads();
    }
    if (tid==0) fvec[b*256+co] = red[0] * (1.f/900.f);
}

// ---------------- K3: MLP + kernel-prediction head ---------------------------
__global__ __launch_bounds__(256) void k_mlp(
    const float* __restrict__ fvec,
    const float* __restrict__ mw1, const float* __restrict__ mb1,
    const float* __restrict__ mw2, const float* __restrict__ mb2,
    const float* __restrict__ kw1, const float* __restrict__ kw2,
    float* __restrict__ kern)
{
    __shared__ float fs[256], h1[256], emb[256], k1[128];
    int b = blockIdx.x, t = threadIdx.x;
    fs[t] = fvec[b*256+t];
    __syncthreads();
    {
        float acc = mb1[t];
        const float* wr = mw1 + t*256;
        for (int i=0;i<256;++i) acc += fs[i]*wr[i];
        h1[t] = lrelu_f(acc);
    }
    __syncthreads();
    {
        float acc = mb2[t];
        const float* wr = mw2 + t*256;
        for (int i=0;i<256;++i) acc += h1[i]*wr[i];
        emb[t] = acc;
    }
    __syncthreads();
    if (t < 128){
        float acc = 0.f;
        const float* wr = kw1 + t*256;
        for (int i=0;i<256;++i) acc += emb[i]*wr[i];
        k1[t] = lrelu_f(acc);
    }
    __syncthreads();
    for (int o=t; o<576; o+=256){
        float acc = 0.f;
        const float* wr = kw2 + o*128;
        for (int i=0;i<128;++i) acc += k1[i]*wr[i];
        kern[b*576+o] = acc;
    }
}

// ---------------- K4: fused {dyn depthwise + 1x1 + CA + combine}, MFMA --------
// Block: 4x16 px tile, 4 waves. GEMMs over the 64-px tile:
//   a1 = lrelu(caw1[32x64] . X[64ci x 64px])       (2 MFMA tiles/wave, K=64)
//   dyn = cw[64x64] . D[64ci x 64px]               (wave w: co-block w, K=64)
//   att = relu(caw2[64x32] . a1[32 x 64px])        (wave w: co-block w, K=32)
//   pre = lrelu(dyn + cb + x*att)  -> bf16 buf
__global__ __launch_bounds__(256) void k_fuse(
    const float* __restrict__ x, const float* __restrict__ kern,
    const float* __restrict__ cw, const float* __restrict__ cb,
    const float* __restrict__ caw1, const float* __restrict__ caw2,
    __hip_bfloat16* __restrict__ buf)
{
    __shared__ __align__(16) char lA [6*18*128];   // x tile [r][c][slot^(c&7)][8ci]
    __shared__ __align__(16) char lD [64*128];     // dw    [px][slot^(px&7)][8ci]
    __shared__ __align__(16) char lA1[64*64];      // a1    [px][slot^(px&3)][8j]
    __shared__ __align__(16) char lW1[64*128];     // cw    [co][slot^(co&7)][8ci]
    __shared__ __align__(16) char lWc[32*128];     // caw1  [co][slot^(co&7)][8ci]
    __shared__ __align__(16) char lW2[64*64];      // caw2  [co][slot^(co&3)][8j]
    __shared__ float kern_s[576];

    const int tid = threadIdx.x;
    const int wid = tid >> 6, lane = tid & 63;
    const int l15 = lane & 15, lg = lane >> 4;
    const int b = blockIdx.y;
    const int toh = (blockIdx.x >> 4) * 4;          // 64 row-tiles
    const int tow = (blockIdx.x & 15) * 16;         // 16 col-tiles
    const int row0 = toh - 1, col0 = tow - 1;

    // ---- stage ----------------------------------------------------------------
    for (int i = tid; i < 6*18*64; i += 256){
        int c  = i % 18;
        int t  = i / 18;
        int r  = t % 6;
        int ci = t / 6;
        int ih = row0 + r, iw = col0 + c;
        unsigned short bits = 0;
        if (ih >= 0 && ih < 256 && iw >= 0 && iw < 256)
            bits = bf_bits(x[((size_t)(b*64+ci) << 16) + ih*256 + iw]);
        *(unsigned short*)(lA + ((r*18+c)*8 + ((ci>>3) ^ (c&7)))*16 + (ci&7)*2) = bits;
    }
    for (int i = tid; i < 4096; i += 256){          // cw [co][ci]
        int co = i >> 6, ci = i & 63;
        *(unsigned short*)(lW1 + (co*8 + ((ci>>3) ^ (co&7)))*16 + (ci&7)*2) = bf_bits(cw[co*64+ci]);
    }
    for (int i = tid; i < 2048; i += 256){          // caw1 [32co][64ci]
        int co = i >> 6, ci = i & 63;
        *(unsigned short*)(lWc + (co*8 + ((ci>>3) ^ (co&7)))*16 + (ci&7)*2) = bf_bits(caw1[co*64+ci]);
    }
    for (int i = tid; i < 2048; i += 256){          // caw2 [64co][32j]
        int co = i >> 5, j = i & 31;
        *(unsigned short*)(lW2 + (co*4 + ((j>>3) ^ (co&3)))*16 + (j&7)*2) = bf_bits(caw2[co*32+j]);
    }
    for (int i = tid; i < 576; i += 256) kern_s[i] = kern[b*576 + i];
    __syncthreads();

    // ---- a1 GEMM (reads lA, lWc only) ----------------------------------------
    const int m1 = wid & 1;                 // a1 row-block
    const int nb = (wid >> 1) * 2;          // px groups nb, nb+1
    f32x4 a1acc[2] = {{0.f,0.f,0.f,0.f},{0.f,0.f,0.f,0.f}};
    const int coA1 = m1*16 + l15;
    #pragma unroll
    for (int ch = 0; ch < 2; ++ch){
        bf16x8 aA = *(const bf16x8*)(lWc + (coA1*8 + ((ch*4+lg) ^ (coA1&7)))*16);
        #pragma unroll
        for (int t = 0; t < 2; ++t){
            int n = nb + t;
            int cc = l15 + 1, rr = n + 1;
            bf16x8 bX = *(const bf16x8*)(lA + ((rr*18+cc)*8 + ((ch*4+lg) ^ (cc&7)))*16);
            a1acc[t] = __builtin_amdgcn_mfma_f32_16x16x32_bf16(aA, bX, a1acc[t], 0,0,0);
        }
    }

    // ---- depthwise -> lD (reads lA, kern_s) ----------------------------------
    {
        const int px = tid & 63;
        const int prow = px >> 4, pcol = px & 15;
        const int ci0 = (tid >> 6) * 16;
        #pragma unroll
        for (int j = 0; j < 16; ++j){
            int ci = ci0 + j;
            const float* kr = kern_s + ci*9;
            float acc = 0.f;
            #pragma unroll
            for (int kh = 0; kh < 3; ++kh)
                #pragma unroll
                for (int kw = 0; kw < 3; ++kw){
                    int r = prow + kh, c = pcol + kw;
                    float xv = bf_val(lA + ((r*18+c)*8 + ((ci>>3) ^ (c&7)))*16 + (ci&7)*2);
                    acc += xv * kr[kh*3+kw];
                }
            *(unsigned short*)(lD + (px*8 + ((ci>>3) ^ (px&7)))*16 + (ci&7)*2)
                = bf_bits(lrelu_f(acc));
        }
    }

    // ---- a1 -> lrelu -> lA1 ---------------------------------------------------
    #pragma unroll
    for (int t = 0; t < 2; ++t){
        int n = nb + t;
        int px = n*16 + l15;
        #pragma unroll
        for (int r = 0; r < 4; ++r){
            int j = m1*16 + lg*4 + r;
            *(unsigned short*)(lA1 + (px*4 + ((j>>3) ^ (px&3)))*16 + (j&7)*2)
                = bf_bits(lrelu_f(a1acc[t][r]));
        }
    }
    __syncthreads();

    // ---- dyn & att GEMMs ------------------------------------------------------
    f32x4 dynacc[4] = {{0.f,0.f,0.f,0.f},{0.f,0.f,0.f,0.f},{0.f,0.f,0.f,0.f},{0.f,0.f,0.f,0.f}};
    f32x4 attacc[4] = {{0.f,0.f,0.f,0.f},{0.f,0.f,0.f,0.f},{0.f,0.f,0.f,0.f},{0.f,0.f,0.f,0.f}};
    const int coA = wid*16 + l15;
    #pragma unroll
    for (int ch = 0; ch < 2; ++ch){
        bf16x8 aW = *(const bf16x8*)(lW1 + (coA*8 + ((ch*4+lg) ^ (coA&7)))*16);
        #pragma unroll
        for (int n = 0; n < 4; ++n){
            int px = n*16 + l15;
            bf16x8 bD = *(const bf16x8*)(lD + (px*8 + ((ch*4+lg) ^ (px&7)))*16);
            dynacc[n] = __builtin_amdgcn_mfma_f32_16x16x32_bf16(aW, bD, dynacc[n], 0,0,0);
        }
    }
    {
        bf16x8 aW2 = *(const bf16x8*)(lW2 + (coA*4 + (lg ^ (coA&3)))*16);
        #pragma unroll
        for (int n = 0; n < 4; ++n){
            int px = n*16 + l15;
            bf16x8 bA1 = *(const bf16x8*)(lA1 + (px*4 + (lg ^ (px&3)))*16);
            attacc[n] = __builtin_amdgcn_mfma_f32_16x16x32_bf16(aW2, bA1, attacc[n], 0,0,0);
        }
    }

    // ---- epilogue: pre = lrelu(dyn + cb + x*relu(att)) -> bf16 buf -----------
    #pragma unroll
    for (int n = 0; n < 4; ++n){
        int oh = toh + n, ow = tow + l15;
        #pragma unroll
        for (int r = 0; r < 4; ++r){
            int co = wid*16 + lg*4 + r;
            size_t oi = ((size_t)(b*64+co) << 16) + oh*256 + ow;
            float att = fmaxf(attacc[n][r], 0.f);
            float v = lrelu_f(dynacc[n][r] + cb[co] + x[oi]*att);
            buf[oi] = __float2bfloat16(v);
        }
    }
}

// ---------------- K5: MFMA implicit-GEMM 64->64 3x3 conv ----------------------
template<typename TIN, int STRIDE, int RESMODE, int ACT, int OUTBF>
__global__ __launch_bounds__(256) void k_conv_mfma(
    const TIN* __restrict__ in, const float* __restrict__ w,
    const float* __restrict__ bias, const void* __restrict__ res,
    void* __restrict__ outp, int H, int W, int Ho, int Wo)
{
    constexpr int ROWS = (STRIDE==1) ? 6 : 9;
    constexpr int COLS = (STRIDE==1) ? 18 : 33;
    __shared__ __align__(16) char lA[ROWS*COLS*8*16];
    __shared__ __align__(16) char lW[64*4*16];
    const int tid  = threadIdx.x;
    const int wid  = tid >> 6, lane = tid & 63;
    const int b    = blockIdx.y;
    const int tilesW = Wo >> 4;
    const int toh  = (blockIdx.x / tilesW) * 4;
    const int tow  = (blockIdx.x % tilesW) * 16;
    const int row0 = toh*STRIDE - 1;
    const int col0 = tow*STRIDE - 1;

    for (int i = tid; i < ROWS*COLS*64; i += 256){
        int c  = i % COLS;
        int t  = i / COLS;
        int r  = t % ROWS;
        int ci = t / ROWS;
        int ih = row0 + r, iw = col0 + c;
        unsigned short bits = 0;
        if (ih >= 0 && ih < H && iw >= 0 && iw < W)
            bits = bf_bits(in[((size_t)(b*64+ci))*H*W + (size_t)ih*W + iw]);
        int slot = ci >> 3, e = ci & 7;
        *(unsigned short*)(lA + ((r*COLS + c)*8 + (slot ^ (c & 7)))*16 + e*2) = bits;
    }
    f32x4 acc[4] = {{0.f,0.f,0.f,0.f},{0.f,0.f,0.f,0.f},{0.f,0.f,0.f,0.f},{0.f,0.f,0.f,0.f}};
    __syncthreads();

    const int px  = lane & 15;
    const int g   = lane >> 4;
    const int coA = wid*16 + (lane & 15);
    const int wAoff = (coA*4 + (g ^ ((coA>>1)&3)))*16;

    for (int ch = 0; ch < 2; ++ch){
        #pragma unroll
        for (int pos = 0; pos < 9; ++pos){
            for (int i = tid; i < 2048; i += 256){
                int co = i >> 5, cil = i & 31;
                float wv = w[((size_t)co*64 + ch*32 + cil)*9 + pos];
                int slot = cil >> 3, e = cil & 7;
                *(unsigned short*)(lW + (co*4 + (slot ^ ((co>>1)&3)))*16 + e*2) = bf_bits(wv);
            }
            __syncthreads();
            const int kh = pos/3, kw = pos - 3*(pos/3);
            bf16x8 aw = *(const bf16x8*)(lW + wAoff);
            const int cc = px*STRIDE + kw;
            const int boff = ((ch*4 + g) ^ (cc & 7))*16;
            #pragma unroll
            for (int n = 0; n < 4; ++n){
                int rr = n*STRIDE + kh;
                bf16x8 bx = *(const bf16x8*)(lA + (rr*COLS + cc)*128 + boff);
                acc[n] = __builtin_amdgcn_mfma_f32_16x16x32_bf16(aw, bx, acc[n], 0, 0, 0);
            }
            __syncthreads();
        }
    }

    const int coBase = wid*16 + g*4;
    #pragma unroll
    for (int n = 0; n < 4; ++n){
        int oh = toh + n, ow = tow + px;
        #pragma unroll
        for (int r = 0; r < 4; ++r){
            int co = coBase + r;
            size_t oi = ((size_t)(b*64+co)*Ho + oh)*Wo + ow;
            float v = acc[n][r] + bias[co];
            if (ACT) v = fmaxf(v, 0.f);
            if (RESMODE == 1) v += ((const float*)res)[oi];
            if (RESMODE == 2) v += __bfloat162float(((const __hip_bfloat16*)res)[oi]);
            if (OUTBF) ((__hip_bfloat16*)outp)[oi] = __float2bfloat16(v);
            else       ((float*)outp)[oi] = v;
        }
    }
}

// ---------------- host ---------------------------------------------------------
extern "C" void kernel_launch(void* const* d_in, const int* in_sizes, int n_in,
                              void* d_out, int out_size, void* d_ws, size_t ws_size,
                              hipStream_t stream) {
    const float* x    = (const float*)d_in[0];
    const float* y    = (const float*)d_in[1];
    const float* ew1  = (const float*)d_in[2];
    const float* eb1  = (const float*)d_in[3];
    const float* bn1g = (const float*)d_in[4];
    const float* bn1b = (const float*)d_in[5];
    const float* bn1m = (const float*)d_in[6];
    const float* bn1v = (const float*)d_in[7];
    const float* ew2  = (const float*)d_in[8];
    const float* eb2  = (const float*)d_in[9];
    const float* bn2g = (const float*)d_in[10];
    const float* bn2b = (const float*)d_in[11];
    const float* bn2m = (const float*)d_in[12];
    const float* bn2v = (const float*)d_in[13];
    const float* mw1  = (const float*)d_in[14];
    const float* mb1  = (const float*)d_in[15];
    const float* mw2  = (const float*)d_in[16];
    const float* mb2  = (const float*)d_in[17];
    const float* kw1  = (const float*)d_in[18];
    const float* kw2  = (const float*)d_in[19];
    const float* cw   = (const float*)d_in[20];
    const float* cb   = (const float*)d_in[21];
    const float* caw1 = (const float*)d_in[22];
    const float* caw2 = (const float*)d_in[23];
    const float* c1w  = (const float*)d_in[24];
    const float* c1b  = (const float*)d_in[25];
    const float* c2w  = (const float*)d_in[26];
    const float* c2b  = (const float*)d_in[27];
    const float* r1w  = (const float*)d_in[28];
    const float* r1b  = (const float*)d_in[29];
    const float* r2w  = (const float*)d_in[30];
    const float* r2b  = (const float*)d_in[31];

    // ws layout (~33.6 MB): buf bf16 [0, 33554432); e1 f32 overlays [0, 2097152);
    // after buf dies: t2 bf16 [0, 8388608), u2 [8388608, 16777216),
    //                 t3 [16777216, 18874368), u3 [18874368, 20971520)
    // fv f32 @ 33554432, kern f32 @ 33558528
    char* wsc = (char*)d_ws;
    __hip_bfloat16* buf = (__hip_bfloat16*)wsc;
    float*          e1  = (float*)wsc;
    __hip_bfloat16* t2  = (__hip_bfloat16*)wsc;
    __hip_bfloat16* u2  = (__hip_bfloat16*)(wsc + 8388608);
    __hip_bfloat16* t3  = (__hip_bfloat16*)(wsc + 16777216);
    __hip_bfloat16* u3  = (__hip_bfloat16*)(wsc + 18874368);
    float*          fv  = (float*)(wsc + 33554432);
    float*          kern= (float*)(wsc + 33558528);

    float* ob   = (float*)d_out;            // out  (4,64,256,256) f32
    float* ob1  = ob + 16777216;            // out2 (4,64,128,128) f32
    float* ob2  = ob + 20971520;            // out3 (4,64,64,64)   f32

    k_enc1<<<dim3(2048),256,0,stream>>>(y, ew1, eb1, bn1g, bn1b, bn1m, bn1v, e1);
    k_enc2<<<dim3(256,4),256,0,stream>>>(e1, ew2, eb2, bn2g, bn2b, bn2m, bn2v, fv);
    k_mlp<<<dim3(4),256,0,stream>>>(fv, mw1, mb1, mw2, mb2, kw1, kw2, kern);
    k_fuse<<<dim3(1024,4),256,0,stream>>>(x, kern, cw, cb, caw1, caw2, buf);

    // out0 = conv3x3(pre) + bias + x  -> f32 d_out
    k_conv_mfma<__hip_bfloat16,1,1,0,0><<<dim3(64*16,4),256,0,stream>>>(buf, c1w, c1b, x, ob, 256,256,256,256);
    // t2 = conv3x3 s2 (out0, f32)     -> bf16 ws
    k_conv_mfma<float,2,0,0,1><<<dim3(32*8,4),256,0,stream>>>(ob, c2w, c2b, nullptr, t2, 256,256,128,128);
    // u2 = relu(conv3x3(t2))          -> bf16 ws
    k_conv_mfma<__hip_bfloat16,1,0,1,1><<<dim3(32*8,4),256,0,stream>>>(t2, r1w, r1b, nullptr, u2, 128,128,128,128);
    // out2 = t2 + conv3x3(u2)         -> f32 d_out
    k_conv_mfma<__hip_bfloat16,1,2,0,0><<<dim3(32*8,4),256,0,stream>>>(u2, r2w, r2b, t2, ob1, 128,128,128,128);
    // t3 = conv3x3 s2 (out2, f32)     -> bf16 ws
    k_conv_mfma<float,2,0,0,1><<<dim3(16*4,4),256,0,stream>>>(ob1, c2w, c2b, nullptr, t3, 128,128,64,64);
    // u3 = relu(conv3x3(t3))          -> bf16 ws
    k_conv_mfma<__hip_bfloat16,1,0,1,1><<<dim3(16*4,4),256,0,stream>>>(t3, r1w, r1b, nullptr, u3, 64,64,64,64);
    // out3 = t3 + conv3x3(u3)         -> f32 d_out
    k_conv_mfma<__hip_bfloat16,1,2,0,0><<<dim3(16*4,4),256,0,stream>>>(u3, r2w, r2b, t3, ob2, 64,64,64,64);
}